// Round 9
// baseline (256.041 us; speedup 1.0000x reference)
//
#include <hip/hip_runtime.h>
#include <hip/hip_cooperative_groups.h>

namespace cg = cooperative_groups;

// CostMapLayer counting-sort, R9: single cooperative kernel (init + scatter +
// grid.sync + aggregate). Phase bodies identical to R8. Removes pInit dispatch
// and two inter-kernel graph-node boundaries.

#define CHUNK 4096
#define TPB 512
#define NIT 4                        // 4 iterations x 2 points = 8 points/thread
#define GRID_F 512                   // fused grid = NBINS
constexpr int HH = 512, WW = 512;
constexpr int NBINS = 512;           // B(8) x 64 tiles of 64x64 cells
constexpr int CAP = 16384;           // per-bin slot capacity (mean ~7.3k valid)

__device__ __forceinline__ unsigned f2ord(float f) {
    unsigned u = __float_as_uint(f);
    return (u & 0x80000000u) ? ~u : (u | 0x80000000u);
}
__device__ __forceinline__ float ord2f(unsigned u) {
    return __uint_as_float((u & 0x80000000u) ? (u & 0x7FFFFFFFu) : ~u);
}

__global__ __launch_bounds__(TPB) void kFused(const float4* __restrict__ pts4,
                                              const float2* __restrict__ cst2,
                                              unsigned* __restrict__ gcur,
                                              unsigned* __restrict__ sorted,
                                              const float* __restrict__ def,
                                              float* __restrict__ out_cost,
                                              float* __restrict__ out_mask,
                                              int npts, int N, int NB) {
    __shared__ unsigned smem[8192];            // 32 KB, aliased per phase
    unsigned* hist  = smem;                    // [512]  (scatter)
    unsigned* gbase = smem + 512;              // [512]  (scatter)
    unsigned* mn    = smem;                    // [4096] (aggregate)
    unsigned* ct    = smem + 4096;             // [4096] (aggregate)
    cg::grid_group grid = cg::this_grid();
    const int t = threadIdx.x;

    // ---- phase 0: init per-bin cursors ----
    if (t == 0) gcur[blockIdx.x] = (unsigned)(blockIdx.x * CAP);   // GRID_F == NBINS
    grid.sync();

    // ---- phase 1: scatter chunks (R8 body) ----
    for (int chunk = blockIdx.x; chunk < NB; chunk += GRID_F) {
        hist[t] = 0u;
        __syncthreads();

        const int base = chunk * CHUNK;            // even
        const int vbase = base >> 1;
        const int b0 = base / N;                   // CHUNK < N: at most one boundary
        const int boundary = (b0 + 1) * N;

        unsigned rec[2 * NIT];     // (lc<<20)|(ordcost>>12)
        unsigned pack[2 * NIT];    // (bin<<12)|rank, ~0u = invalid

        int g = vbase + t;
        bool in0 = (base + 2 * t) < npts;
        float4 P = in0 ? pts4[g] : make_float4(-100.f, -100.f, -100.f, -100.f);
        float2 C = in0 ? cst2[g] : make_float2(0.f, 0.f);
#pragma unroll
        for (int k = 0; k < NIT; ++k) {
            float4 Pc = P;
            float2 Cc = C;
            const int idx0 = base + 2 * (k * TPB + t);
            if (k + 1 < NIT) {                     // prefetch next iteration
                int gn = vbase + (k + 1) * TPB + t;
                bool in = (base + 2 * ((k + 1) * TPB + t)) < npts;
                P = in ? pts4[gn] : make_float4(-100.f, -100.f, -100.f, -100.f);
                C = in ? cst2[gn] : make_float2(0.f, 0.f);
            }
#pragma unroll
            for (int j = 0; j < 2; ++j) {
                const int idx = idx0 + j;
                const float px = j ? Pc.z : Pc.x;
                const float py = j ? Pc.w : Pc.y;
                const float cv = j ? Cc.y : Cc.x;
                int ix = (int)floorf(px + 0.5f);   // HALF_CENTOR
                int iy = (int)floorf(py + 0.5f);
                unsigned pk = 0xFFFFFFFFu, rc = 0u;
                if (ix >= 0 && ix < WW && iy >= 0 && iy < HH) {
                    int b = (idx >= boundary) ? b0 + 1 : b0;
                    unsigned bin = (unsigned)(b * 64 + ((iy >> 6) << 3) + (ix >> 6));
                    unsigned lc  = (unsigned)(((iy & 63) << 6) | (ix & 63));
                    unsigned rank = atomicAdd(&hist[bin], 1u);
                    pk = (bin << 12) | rank;       // rank < 4096
                    rc = (lc << 20) | (f2ord(cv) >> 12);
                }
                rec[2 * k + j]  = rc;
                pack[2 * k + j] = pk;
            }
        }
        __syncthreads();

        gbase[t] = atomicAdd(&gcur[t], hist[t]);   // reserve contiguous run
        __syncthreads();

#pragma unroll
        for (int k = 0; k < 2 * NIT; ++k) {
            if (pack[k] != 0xFFFFFFFFu) {
                unsigned bin = pack[k] >> 12, rank = pack[k] & 4095u;
                unsigned slot = gbase[bin] + rank;
                if (slot < (bin + 1u) * CAP)       // overflow guard (never fires)
                    sorted[slot] = rec[k];
            }
        }
        __syncthreads();                           // gbase stable until next reserve
    }
    grid.sync();

    // ---- phase 2: aggregate bin = blockIdx.x (R8 pD body) ----
    const int bin = blockIdx.x;
#pragma unroll
    for (int i = t; i < 4096; i += TPB) { mn[i] = 0xFFFFFFFFu; ct[i] = 0u; }
    __syncthreads();
    const unsigned s0 = (unsigned)bin * CAP;
    const unsigned e  = gcur[bin];
    const unsigned s1 = (e < s0 + CAP) ? e : s0 + CAP;
    for (unsigned i = s0 + t; i < s1; i += TPB) {
        unsigned v = sorted[i];
        atomicMin(&mn[v >> 20], v & 0xFFFFFu);
        atomicAdd(&ct[v >> 20], 1u);
    }
    __syncthreads();
    const float d = *def;
    const int b = bin >> 6, tile = bin & 63, ty = tile >> 3, tx = tile & 7;
    const int r = t >> 3, c0 = (t & 7) * 8;
    const int o0 = (b * HH + ty * 64 + r) * WW + tx * 64 + c0;
#pragma unroll
    for (int v4 = 0; v4 < 2; ++v4) {
        float4 oc, om;
        float* pc = (float*)&oc;
        float* pm = (float*)&om;
#pragma unroll
        for (int j = 0; j < 4; ++j) {
            int i = r * 64 + c0 + v4 * 4 + j;
            unsigned cc = ct[i];
            pc[j] = cc ? ord2f((mn[i] << 12) | 0x800u) : d;
            pm[j] = (float)((int)cc - 1);
        }
        *(float4*)(out_cost + o0 + v4 * 4) = oc;
        *(float4*)(out_mask + o0 + v4 * 4) = om;
    }
}

// ---------------- non-cooperative 3-kernel path (R8) ----------------
__global__ void pInit(unsigned* __restrict__ gcur) {
    gcur[threadIdx.x] = (unsigned)(threadIdx.x * CAP);
}

__global__ __launch_bounds__(TPB) void pS(const float4* __restrict__ pts4,
                                          const float2* __restrict__ cst2,
                                          unsigned* __restrict__ gcur,
                                          unsigned* __restrict__ sorted,
                                          int npts, int N) {
    __shared__ unsigned hist[NBINS];
    __shared__ unsigned gbase[NBINS];
    const int t = threadIdx.x, blk = blockIdx.x;
    hist[t] = 0u;
    __syncthreads();
    const int base = blk * CHUNK;
    const int vbase = base >> 1;
    const int b0 = base / N;
    const int boundary = (b0 + 1) * N;
    unsigned rec[2 * NIT], pack[2 * NIT];
    int g = vbase + t;
    bool in0 = (base + 2 * t) < npts;
    float4 P = in0 ? pts4[g] : make_float4(-100.f, -100.f, -100.f, -100.f);
    float2 C = in0 ? cst2[g] : make_float2(0.f, 0.f);
#pragma unroll
    for (int k = 0; k < NIT; ++k) {
        float4 Pc = P;
        float2 Cc = C;
        const int idx0 = base + 2 * (k * TPB + t);
        if (k + 1 < NIT) {
            int gn = vbase + (k + 1) * TPB + t;
            bool in = (base + 2 * ((k + 1) * TPB + t)) < npts;
            P = in ? pts4[gn] : make_float4(-100.f, -100.f, -100.f, -100.f);
            C = in ? cst2[gn] : make_float2(0.f, 0.f);
        }
#pragma unroll
        for (int j = 0; j < 2; ++j) {
            const int idx = idx0 + j;
            const float px = j ? Pc.z : Pc.x;
            const float py = j ? Pc.w : Pc.y;
            const float cv = j ? Cc.y : Cc.x;
            int ix = (int)floorf(px + 0.5f);
            int iy = (int)floorf(py + 0.5f);
            unsigned pk = 0xFFFFFFFFu, rc = 0u;
            if (ix >= 0 && ix < WW && iy >= 0 && iy < HH) {
                int b = (idx >= boundary) ? b0 + 1 : b0;
                unsigned bin = (unsigned)(b * 64 + ((iy >> 6) << 3) + (ix >> 6));
                unsigned lc  = (unsigned)(((iy & 63) << 6) | (ix & 63));
                unsigned rank = atomicAdd(&hist[bin], 1u);
                pk = (bin << 12) | rank;
                rc = (lc << 20) | (f2ord(cv) >> 12);
            }
            rec[2 * k + j]  = rc;
            pack[2 * k + j] = pk;
        }
    }
    __syncthreads();
    gbase[t] = atomicAdd(&gcur[t], hist[t]);
    __syncthreads();
#pragma unroll
    for (int k = 0; k < 2 * NIT; ++k) {
        if (pack[k] != 0xFFFFFFFFu) {
            unsigned bin = pack[k] >> 12, rank = pack[k] & 4095u;
            unsigned slot = gbase[bin] + rank;
            if (slot < (bin + 1u) * CAP)
                sorted[slot] = rec[k];
        }
    }
}

__global__ __launch_bounds__(TPB) void pD(const unsigned* __restrict__ sorted,
                                          const unsigned* __restrict__ gcur,
                                          const float* __restrict__ def,
                                          float* __restrict__ out_cost,
                                          float* __restrict__ out_mask) {
    __shared__ unsigned mn[4096];
    __shared__ unsigned ct[4096];
    const int bin = blockIdx.x, t = threadIdx.x;
#pragma unroll
    for (int i = t; i < 4096; i += TPB) { mn[i] = 0xFFFFFFFFu; ct[i] = 0u; }
    __syncthreads();
    const unsigned s0 = (unsigned)bin * CAP;
    const unsigned e  = gcur[bin];
    const unsigned s1 = (e < s0 + CAP) ? e : s0 + CAP;
    for (unsigned i = s0 + t; i < s1; i += TPB) {
        unsigned v = sorted[i];
        atomicMin(&mn[v >> 20], v & 0xFFFFFu);
        atomicAdd(&ct[v >> 20], 1u);
    }
    __syncthreads();
    const float d = *def;
    const int b = bin >> 6, tile = bin & 63, ty = tile >> 3, tx = tile & 7;
    const int r = t >> 3, c0 = (t & 7) * 8;
    const int o0 = (b * HH + ty * 64 + r) * WW + tx * 64 + c0;
#pragma unroll
    for (int v4 = 0; v4 < 2; ++v4) {
        float4 oc, om;
        float* pc = (float*)&oc;
        float* pm = (float*)&om;
#pragma unroll
        for (int j = 0; j < 4; ++j) {
            int i = r * 64 + c0 + v4 * 4 + j;
            unsigned cc = ct[i];
            pc[j] = cc ? ord2f((mn[i] << 12) | 0x800u) : d;
            pm[j] = (float)((int)cc - 1);
        }
        *(float4*)(out_cost + o0 + v4 * 4) = oc;
        *(float4*)(out_mask + o0 + v4 * 4) = om;
    }
}

// ---------------- fallback: global-atomic path ----------------
__global__ void fb_init(uint2* __restrict__ cells, int nseg) {
    int i = blockIdx.x * blockDim.x + threadIdx.x;
    int stride = gridDim.x * blockDim.x;
    for (; i < nseg; i += stride) cells[i] = make_uint2(0xFFFFFFFFu, 0u);
}
__global__ void fb_scatter(const float2* __restrict__ pts, const float* __restrict__ costs,
                           uint2* __restrict__ cells, int npts, int N, int H, int W) {
    int i = blockIdx.x * blockDim.x + threadIdx.x;
    if (i >= npts) return;
    float2 p = pts[i];
    int ix = (int)floorf(p.x + 0.5f), iy = (int)floorf(p.y + 0.5f);
    if (ix < 0 || ix >= W || iy < 0 || iy >= H) return;
    int b = i / N;
    atomicMin(&cells[(b * H + iy) * W + ix].x, f2ord(costs[i]));
    atomicAdd(&cells[(b * H + iy) * W + ix].y, 1u);
}
__global__ void fb_final(const uint2* __restrict__ cells, const float* __restrict__ def,
                         float* __restrict__ oc, float* __restrict__ om, int nseg) {
    int i = blockIdx.x * blockDim.x + threadIdx.x;
    if (i >= nseg) return;
    uint2 c = cells[i];
    float d = *def;
    oc[i] = c.y ? ord2f(c.x) : d;
    om[i] = (float)((int)c.y - 1);
}

extern "C" void kernel_launch(void* const* d_in, const int* in_sizes, int n_in,
                              void* d_out, int out_size, void* d_ws, size_t ws_size,
                              hipStream_t stream) {
    const float2* pts = (const float2*)d_in[0];
    const float*  cst = (const float*)d_in[1];
    const float*  def = (const float*)d_in[2];

    const int npts = in_sizes[1];          // B*N
    const int nseg = out_size / 2;         // B*H*W
    const int B    = nseg / (HH * WW);
    const int N    = npts / B;
    float* out_cost = (float*)d_out;
    float* out_mask = out_cost + nseg;

    const int NB = (npts + CHUNK - 1) / CHUNK;
    const size_t sorted_bytes = (size_t)NBINS * CAP * 4;
    const size_t need = sorted_bytes + NBINS * 4;
    const bool cap_ok = (npts / NBINS) * 2 <= CAP;

    if (B == 8 && nseg == 8 * HH * WW && ws_size >= need && N > CHUNK &&
        cap_ok && (npts % 2) == 0) {
        unsigned* sorted = (unsigned*)d_ws;
        unsigned* gcur   = (unsigned*)((char*)d_ws + sorted_bytes);

        const float4* pts4 = (const float4*)pts;
        const float2* cst2 = (const float2*)cst;
        int npts_v = npts, N_v = N, NB_v = NB;
        void* args[] = {(void*)&pts4, (void*)&cst2, (void*)&gcur, (void*)&sorted,
                        (void*)&def, (void*)&out_cost, (void*)&out_mask,
                        (void*)&npts_v, (void*)&N_v, (void*)&NB_v};
        hipError_t err = hipLaunchCooperativeKernel((const void*)kFused,
                                                    dim3(GRID_F), dim3(TPB),
                                                    args, 0, stream);
        if (err != hipSuccess) {
            pInit<<<1,     TPB, 0, stream>>>(gcur);
            pS   <<<NB,    TPB, 0, stream>>>(pts4, cst2, gcur, sorted, npts, N);
            pD   <<<NBINS, TPB, 0, stream>>>(sorted, gcur, def, out_cost, out_mask);
        }
    } else {
        uint2* cells = (uint2*)d_ws;
        fb_init   <<<2048, 256, 0, stream>>>(cells, nseg);
        fb_scatter<<<(npts + 255) / 256, 256, 0, stream>>>(pts, cst, cells, npts, N, HH, WW);
        fb_final  <<<(nseg + 255) / 256, 256, 0, stream>>>(cells, def, out_cost, out_mask, nseg);
    }
}

// Round 10
// 121.472 us; speedup vs baseline: 2.1078x; 2.1078x over previous
//
#include <hip/hip_runtime.h>

// CostMapLayer counting-sort, R10: revert R9's cooperative fusion (163 µs vs
// 55 µs — lost TLP). Best-known 3-kernel structure (R8 pS body) + CHUNK=8192
// (halves contended global reservation atomics: 500k -> 250k, per R5 evidence).
// pack = (bin<<13)|rank  (rank < CHUNK = 8192).

#define CHUNK 8192
#define TPB 512
#define NIT 8                        // 8 iterations x 2 points = 16 points/thread
constexpr int HH = 512, WW = 512;
constexpr int NBINS = 512;           // B(8) x 64 tiles of 64x64 cells
constexpr int CAP = 16384;           // per-bin slot capacity (mean ~7.3k valid)

__device__ __forceinline__ unsigned f2ord(float f) {
    unsigned u = __float_as_uint(f);
    return (u & 0x80000000u) ? ~u : (u | 0x80000000u);
}
__device__ __forceinline__ float ord2f(unsigned u) {
    return __uint_as_float((u & 0x80000000u) ? (u & 0x7FFFFFFFu) : ~u);
}

// ---------------- init: per-bin write cursors ----------------
__global__ void pInit(unsigned* __restrict__ gcur) {
    gcur[threadIdx.x] = (unsigned)(threadIdx.x * CAP);   // 1 block x 512
}

// ---------------- pS: pipelined histogram(rank) + reserve + scatter ----------------
__global__ __launch_bounds__(TPB) void pS(const float4* __restrict__ pts4,
                                          const float2* __restrict__ cst2,
                                          unsigned* __restrict__ gcur,
                                          unsigned* __restrict__ sorted,
                                          int npts, int N) {
    __shared__ unsigned hist[NBINS];
    __shared__ unsigned gbase[NBINS];
    const int t = threadIdx.x, blk = blockIdx.x;
    hist[t] = 0u;                                 // TPB == NBINS
    __syncthreads();

    const int base = blk * CHUNK;                 // point index base (even)
    const int vbase = base >> 1;                  // float4/float2 index base
    const int b0 = base / N;                      // CHUNK < N: at most one boundary
    const int boundary = (b0 + 1) * N;

    unsigned rec[2 * NIT];    // (lc<<20)|(ordcost>>12)
    unsigned pack[2 * NIT];   // (bin<<13)|rank, ~0u = invalid

    // ---- phase 1: 2-stage pipelined loads + key/rank ----
    int g = vbase + t;
    bool in0 = (base + 2 * t) < npts;
    float4 P = in0 ? pts4[g] : make_float4(-100.f, -100.f, -100.f, -100.f);
    float2 C = in0 ? cst2[g] : make_float2(0.f, 0.f);
#pragma unroll
    for (int k = 0; k < NIT; ++k) {
        float4 Pc = P;
        float2 Cc = C;
        const int idx0 = base + 2 * (k * TPB + t);
        if (k + 1 < NIT) {                        // prefetch next iteration
            int gn = vbase + (k + 1) * TPB + t;
            bool in = (base + 2 * ((k + 1) * TPB + t)) < npts;
            P = in ? pts4[gn] : make_float4(-100.f, -100.f, -100.f, -100.f);
            C = in ? cst2[gn] : make_float2(0.f, 0.f);
        }
#pragma unroll
        for (int j = 0; j < 2; ++j) {
            const int idx = idx0 + j;
            const float px = j ? Pc.z : Pc.x;
            const float py = j ? Pc.w : Pc.y;
            const float cv = j ? Cc.y : Cc.x;
            int ix = (int)floorf(px + 0.5f);      // HALF_CENTOR
            int iy = (int)floorf(py + 0.5f);
            unsigned pk = 0xFFFFFFFFu, rc = 0u;
            if (ix >= 0 && ix < WW && iy >= 0 && iy < HH) {
                int b = (idx >= boundary) ? b0 + 1 : b0;
                unsigned bin = (unsigned)(b * 64 + ((iy >> 6) << 3) + (ix >> 6));
                unsigned lc  = (unsigned)(((iy & 63) << 6) | (ix & 63));
                unsigned rank = atomicAdd(&hist[bin], 1u);
                pk = (bin << 13) | rank;          // rank < CHUNK = 8192
                rc = (lc << 20) | (f2ord(cv) >> 12);
            }
            rec[2 * k + j]  = rc;
            pack[2 * k + j] = pk;
        }
    }
    __syncthreads();

    // ---- phase 2: one global atomic per bin reserves a contiguous run ----
    gbase[t] = atomicAdd(&gcur[t], hist[t]);
    __syncthreads();

    // ---- phase 3: slot = gbase[bin] + rank ----
#pragma unroll
    for (int k = 0; k < 2 * NIT; ++k) {
        if (pack[k] != 0xFFFFFFFFu) {
            unsigned bin = pack[k] >> 13, rank = pack[k] & 8191u;
            unsigned slot = gbase[bin] + rank;
            if (slot < (bin + 1u) * CAP)          // overflow guard (never fires)
                sorted[slot] = rec[k];
        }
    }
}

// ---------------- pD: per-bin LDS aggregate + vectorized final write ----------------
__global__ __launch_bounds__(TPB) void pD(const unsigned* __restrict__ sorted,
                                          const unsigned* __restrict__ gcur,
                                          const float* __restrict__ def,
                                          float* __restrict__ out_cost,
                                          float* __restrict__ out_mask) {
    __shared__ unsigned mn[4096];
    __shared__ unsigned ct[4096];
    const int bin = blockIdx.x, t = threadIdx.x;
#pragma unroll
    for (int i = t; i < 4096; i += TPB) { mn[i] = 0xFFFFFFFFu; ct[i] = 0u; }
    __syncthreads();
    const unsigned s0 = (unsigned)bin * CAP;
    const unsigned e  = gcur[bin];
    const unsigned s1 = (e < s0 + CAP) ? e : s0 + CAP;
    for (unsigned i = s0 + t; i < s1; i += TPB) {
        unsigned v = sorted[i];
        atomicMin(&mn[v >> 20], v & 0xFFFFFu);
        atomicAdd(&ct[v >> 20], 1u);
    }
    __syncthreads();
    const float d = *def;
    const int b = bin >> 6, tile = bin & 63, ty = tile >> 3, tx = tile & 7;
    const int r = t >> 3, c0 = (t & 7) * 8;
    const int o0 = (b * HH + ty * 64 + r) * WW + tx * 64 + c0;
#pragma unroll
    for (int v4 = 0; v4 < 2; ++v4) {
        float4 oc, om;
        float* pc = (float*)&oc;
        float* pm = (float*)&om;
#pragma unroll
        for (int j = 0; j < 4; ++j) {
            int i = r * 64 + c0 + v4 * 4 + j;
            unsigned cc = ct[i];
            pc[j] = cc ? ord2f((mn[i] << 12) | 0x800u) : d;
            pm[j] = (float)((int)cc - 1);
        }
        *(float4*)(out_cost + o0 + v4 * 4) = oc;
        *(float4*)(out_mask + o0 + v4 * 4) = om;
    }
}

// ---------------- fallback: global-atomic path ----------------
__global__ void fb_init(uint2* __restrict__ cells, int nseg) {
    int i = blockIdx.x * blockDim.x + threadIdx.x;
    int stride = gridDim.x * blockDim.x;
    for (; i < nseg; i += stride) cells[i] = make_uint2(0xFFFFFFFFu, 0u);
}
__global__ void fb_scatter(const float2* __restrict__ pts, const float* __restrict__ costs,
                           uint2* __restrict__ cells, int npts, int N, int H, int W) {
    int i = blockIdx.x * blockDim.x + threadIdx.x;
    if (i >= npts) return;
    float2 p = pts[i];
    int ix = (int)floorf(p.x + 0.5f), iy = (int)floorf(p.y + 0.5f);
    if (ix < 0 || ix >= W || iy < 0 || iy >= H) return;
    int b = i / N;
    atomicMin(&cells[(b * H + iy) * W + ix].x, f2ord(costs[i]));
    atomicAdd(&cells[(b * H + iy) * W + ix].y, 1u);
}
__global__ void fb_final(const uint2* __restrict__ cells, const float* __restrict__ def,
                         float* __restrict__ oc, float* __restrict__ om, int nseg) {
    int i = blockIdx.x * blockDim.x + threadIdx.x;
    if (i >= nseg) return;
    uint2 c = cells[i];
    float d = *def;
    oc[i] = c.y ? ord2f(c.x) : d;
    om[i] = (float)((int)c.y - 1);
}

extern "C" void kernel_launch(void* const* d_in, const int* in_sizes, int n_in,
                              void* d_out, int out_size, void* d_ws, size_t ws_size,
                              hipStream_t stream) {
    const float2* pts = (const float2*)d_in[0];
    const float*  cst = (const float*)d_in[1];
    const float*  def = (const float*)d_in[2];

    const int npts = in_sizes[1];          // B*N
    const int nseg = out_size / 2;         // B*H*W
    const int B    = nseg / (HH * WW);
    const int N    = npts / B;
    float* out_cost = (float*)d_out;
    float* out_mask = out_cost + nseg;

    const int NB = (npts + CHUNK - 1) / CHUNK;
    const size_t sorted_bytes = (size_t)NBINS * CAP * 4;
    const size_t need = sorted_bytes + NBINS * 4;
    const bool cap_ok = (npts / NBINS) * 2 <= CAP;

    if (B == 8 && nseg == 8 * HH * WW && ws_size >= need && N > CHUNK &&
        cap_ok && (npts % 2) == 0) {
        unsigned* sorted = (unsigned*)d_ws;
        unsigned* gcur   = (unsigned*)((char*)d_ws + sorted_bytes);

        pInit<<<1,     TPB, 0, stream>>>(gcur);
        pS   <<<NB,    TPB, 0, stream>>>((const float4*)pts, (const float2*)cst,
                                         gcur, sorted, npts, N);
        pD   <<<NBINS, TPB, 0, stream>>>(sorted, gcur, def, out_cost, out_mask);
    } else {
        uint2* cells = (uint2*)d_ws;
        fb_init   <<<2048, 256, 0, stream>>>(cells, nseg);
        fb_scatter<<<(npts + 255) / 256, 256, 0, stream>>>(pts, cst, cells, npts, N, HH, WW);
        fb_final  <<<(nseg + 255) / 256, 256, 0, stream>>>(cells, def, out_cost, out_mask, nseg);
    }
}